// Round 1
// baseline (127.428 us; speedup 1.0000x reference)
//
#include <hip/hip_runtime.h>

// SimpleSNN: out[r][j] = sum over 10 steps of spikes from leaky neuron driven by
// cur[r][j] = dot(x[r,:], W[j,:]).  x:[65536,784] f32, W:[10,784] f32, out f32.
//
// Design: memory-bound (208 MB @ ~6.3 TB/s => ~33us floor).
//  - 256 blocks x 512 threads. Each block owns 256 rows; thread = (row r, col-half h).
//  - x staged in LDS tiles [256 rows x 28 cols], pad stride 29 (conflict-free b32 reads),
//    double-buffered; global loads issued BEFORE compute, ds_writes after (T14 split).
//  - W read via wave-uniform s_load (readfirstlane on h) -> SGPR broadcast, no LDS traffic.
//  - f64 accumulation + f64 recurrence: outputs are integer spike counts; threshold
//    crossings (mem > 1.0) must match the f64 numpy reference exactly.

constexpr int ROWS = 65536;
constexpr int COLS = 784;
constexpr int NOUT = 10;
constexpr int STEPS = 10;

constexpr int BR   = 256;        // rows per block
constexpr int TW   = 28;         // tile width in cols (784 = 28*28)
constexpr int NT   = COLS / TW;  // 28 tiles
constexpr int PADW = TW + 1;     // 29: bank-conflict-free row stride
constexpr int HALF = TW / 2;     // 14 cols per thread-half
constexpr int NF4  = BR * (TW / 4);  // 1792 float4 per tile

__global__ __launch_bounds__(512)
void snn_fused(const float* __restrict__ x, const float* __restrict__ W,
               float* __restrict__ out) {
    __shared__ __align__(16) char smem_raw[2 * BR * PADW * 4];
    float*  tile = reinterpret_cast<float*>(smem_raw);
    double* comb = reinterpret_cast<double*>(smem_raw);  // reused after tile loop

    const int tid  = threadIdx.x;
    const int r    = tid & 255;
    const int h    = tid >> 8;                       // 0: cols 0..13 of tile, 1: 14..27
    const int hu   = __builtin_amdgcn_readfirstlane(h);  // wave-uniform -> s_load for W
    const int row0 = blockIdx.x * BR;

    const float* xblk = x + (size_t)row0 * COLS;

    // ---- staging helpers (4 float4 per thread per tile; k==3 only for tid<256) ----
    float4 sv[4];
    auto issue_loads = [&](int t, float4* v) {
        const float* xb = xblk + t * TW;
        #pragma unroll
        for (int k = 0; k < 4; ++k) {
            int i = tid + 512 * k;
            if (i < NF4) {
                int rr = i / 7;          // row within block
                int c4 = i % 7;          // float4 index within tile row
                v[k] = *reinterpret_cast<const float4*>(xb + (size_t)rr * COLS + c4 * 4);
            }
        }
    };
    auto write_lds = [&](int b, const float4* v) {
        float* dst = tile + b * (BR * PADW);
        #pragma unroll
        for (int k = 0; k < 4; ++k) {
            int i = tid + 512 * k;
            if (i < NF4) {
                int rr = i / 7;
                int c4 = i % 7;
                float* p = dst + rr * PADW + c4 * 4;
                p[0] = v[k].x; p[1] = v[k].y; p[2] = v[k].z; p[3] = v[k].w;
            }
        }
    };

    double acc[NOUT];
    #pragma unroll
    for (int j = 0; j < NOUT; ++j) acc[j] = 0.0;

    // prologue: stage tile 0
    issue_loads(0, sv);
    write_lds(0, sv);
    __syncthreads();

    for (int t = 0; t < NT; ++t) {
        float4 nv[4];
        if (t + 1 < NT) issue_loads(t + 1, nv);   // in flight under compute

        const float* src = tile + (t & 1) * (BR * PADW) + r * PADW + hu * HALF;
        const int    gc0 = t * TW + hu * HALF;    // wave-uniform global col base
        #pragma unroll
        for (int c = 0; c < HALF; ++c) {
            double xd = (double)src[c];           // ds_read_b32, conflict-free
            #pragma unroll
            for (int j = 0; j < NOUT; ++j) {
                double wd = (double)W[j * COLS + gc0 + c];  // s_load + cvt
                acc[j] = fma(xd, wd, acc[j]);
            }
        }

        if (t + 1 < NT) write_lds((t + 1) & 1, nv);  // waits vmcnt here, not earlier
        __syncthreads();
    }

    // ---- combine halves: h=1 dumps partials, h=0 finishes ----
    if (h == 1) {
        #pragma unroll
        for (int j = 0; j < NOUT; ++j) comb[r * NOUT + j] = acc[j];
    }
    __syncthreads();
    if (h == 0) {
        double cur[NOUT];
        #pragma unroll
        for (int j = 0; j < NOUT; ++j) cur[j] = acc[j] + comb[r * NOUT + j];

        float* op = out + (size_t)(row0 + r) * NOUT;
        #pragma unroll
        for (int j = 0; j < NOUT; ++j) {
            double mem = 0.0, spk = 0.0, s = 0.0;
            #pragma unroll
            for (int st = 0; st < STEPS; ++st) {
                mem = 0.95 * mem + cur[j] - spk;   // reset-by-subtraction, thr=1.0
                spk = (mem > 1.0) ? 1.0 : 0.0;
                s  += spk;
            }
            op[j] = (float)s;
        }
    }
}

extern "C" void kernel_launch(void* const* d_in, const int* in_sizes, int n_in,
                              void* d_out, int out_size, void* d_ws, size_t ws_size,
                              hipStream_t stream) {
    const float* x = (const float*)d_in[0];
    const float* W = (const float*)d_in[1];
    float* out = (float*)d_out;
    hipLaunchKernelGGL(snn_fused, dim3(ROWS / BR), dim3(512), 0, stream, x, W, out);
}

// Round 3
// 48.461 us; speedup vs baseline: 2.6295x; 2.6295x over previous
//
#include <hip/hip_runtime.h>

// SimpleSNN: out[r][j] = sum over 10 steps of spikes from a leaky neuron driven by
// cur[r][j] = dot(x[r,:], W[j,:]).  x:[65536,784] f32, W:[10,784] f32, out f32.
//
// R3 = R2 with the epilogue bug fixed: BR*NOUT = 640 outputs but only 512 threads;
// R2's `if (tid < 640)` left rows 51..63 of every block unwritten (absmax 10.0).
// Now a strided loop covers all 640.
//
// Design (R2 rationale, unchanged):
//  - R1 was occupancy-bound (1 block/CU, 23% occ, 27% VALUBusy, hbm 8%).
//  - 1024 blocks x 512 threads; 64 rows/block, 8-way column split (wave h owns
//    cols {t*16 + h*2 + c}).  LDS: 8.7KB x-tile (dbuf) + 40KB combine (union)
//    -> 4 blocks/CU x 8 waves = 32 waves/CU (100%).
//  - W pre-converted to f64 in d_ws; main loop reads it wave-uniformly (s_load,
//    no per-(c,j) v_cvt_f64_f32).
//  - f64 accumulation + recurrence: spike counts must match the np reference
//    exactly (R1 passed with absmax == 0.0); threshold crossings are brittle.

constexpr int ROWS = 65536;
constexpr int COLS = 784;
constexpr int NOUT = 10;
constexpr int STEPS = 10;

constexpr int BR   = 64;          // rows per block
constexpr int TW   = 16;          // tile width (784 = 49*16)
constexpr int NT   = COLS / TW;   // 49 tiles
constexpr int PADW = TW + 1;      // 17: odd stride -> worst 2-way on b32 reads (free)
constexpr int NH   = 8;           // column octants (= waves per block)
constexpr int CPH  = TW / NH;     // 2 cols per thread per tile

__global__ void w_to_f64(const float* __restrict__ W, double* __restrict__ W64) {
    int i = blockIdx.x * 256 + threadIdx.x;
    if (i < NOUT * COLS) W64[i] = (double)W[i];
}

__global__ __launch_bounds__(512, 8)
void snn_fused(const float* __restrict__ x, const double* __restrict__ W64,
               float* __restrict__ out) {
    // union: [2][BR][PADW] f32 x-tiles (8704B)  /  [NH][BR][NOUT] f64 combine (40960B)
    __shared__ __align__(16) char smem[NH * BR * NOUT * 8];
    float*  tile = reinterpret_cast<float*>(smem);
    double* comb = reinterpret_cast<double*>(smem);

    const int tid  = threadIdx.x;
    const int r    = tid & (BR - 1);
    const int h    = tid >> 6;                            // == wave id (0..7)
    const int hu   = __builtin_amdgcn_readfirstlane(h);   // wave-uniform -> SGPR
    const int row0 = blockIdx.x * BR;

    const float* xblk = x + (size_t)row0 * COLS;

    // staging: 256 float4 per tile (64 rows x 16 cols); threads 0..255, one each.
    // per row: 64B contiguous, 64B-aligned (row stride 3136B = 49*64).
    float4 cv;
    auto issue = [&](int t, float4& v) {
        if (tid < BR * TW / 4) {
            int rr = tid >> 2, c4 = tid & 3;
            v = *reinterpret_cast<const float4*>(xblk + (size_t)rr * COLS + t * TW + c4 * 4);
        }
    };
    auto wlds = [&](int b, const float4& v) {
        if (tid < BR * TW / 4) {
            int rr = tid >> 2, c4 = tid & 3;
            float* p = tile + b * (BR * PADW) + rr * PADW + c4 * 4;
            p[0] = v.x; p[1] = v.y; p[2] = v.z; p[3] = v.w;
        }
    };

    double acc[NOUT];
    #pragma unroll
    for (int j = 0; j < NOUT; ++j) acc[j] = 0.0;

    issue(0, cv);
    wlds(0, cv);
    __syncthreads();

    for (int t = 0; t < NT; ++t) {
        float4 nv;
        if (t + 1 < NT) issue(t + 1, nv);                 // HBM latency under compute

        const float*  src = tile + (t & 1) * (BR * PADW) + r * PADW + hu * CPH;
        const double* wb  = W64 + t * TW + hu * CPH;      // wave-uniform -> s_load f64
        #pragma unroll
        for (int c = 0; c < CPH; ++c) {
            double xd = (double)src[c];                   // ds_read_b32 + 1 cvt
            #pragma unroll
            for (int j = 0; j < NOUT; ++j)
                acc[j] = fma(xd, wb[j * COLS + c], acc[j]);
        }

        if (t + 1 < NT) wlds((t + 1) & 1, nv);
        __syncthreads();                                  // 1 barrier per tile
    }

    // combine 8 octant-partials per (row, j), then run the recurrence
    #pragma unroll
    for (int j = 0; j < NOUT; ++j)
        comb[hu * (BR * NOUT) + r * NOUT + j] = acc[j];
    __syncthreads();

    for (int i = tid; i < BR * NOUT; i += 512) {          // 640 outputs, 512 threads
        double cur = 0.0;
        #pragma unroll
        for (int hh = 0; hh < NH; ++hh)
            cur += comb[hh * (BR * NOUT) + i];

        double mem = 0.0, spk = 0.0, s = 0.0;
        #pragma unroll
        for (int st = 0; st < STEPS; ++st) {
            mem = 0.95 * mem + cur - spk;                 // reset-by-subtraction, thr=1.0
            spk = (mem > 1.0) ? 1.0 : 0.0;
            s  += spk;
        }
        out[(size_t)row0 * NOUT + i] = (float)s;          // 2560B coalesced per block
    }
}

extern "C" void kernel_launch(void* const* d_in, const int* in_sizes, int n_in,
                              void* d_out, int out_size, void* d_ws, size_t ws_size,
                              hipStream_t stream) {
    const float* x = (const float*)d_in[0];
    const float* W = (const float*)d_in[1];
    float*  out = (float*)d_out;
    double* W64 = (double*)d_ws;   // 7840 * 8B = 62.7 KB

    hipLaunchKernelGGL(w_to_f64, dim3((NOUT * COLS + 255) / 256), dim3(256), 0, stream, W, W64);
    hipLaunchKernelGGL(snn_fused, dim3(ROWS / BR), dim3(512), 0, stream, x, W64, out);
}